// Round 2
// baseline (723.269 us; speedup 1.0000x reference)
//
#include <hip/hip_runtime.h>
#include <hip/hip_bf16.h>
#include <math.h>

// Problem constants
// B=8, Cin=128, Cout=128, H=W=64, K=3, S=1, P=1
// x:        [8][128][64][64]  fp32   (4,194,304)
// w_offset: [18][128][3][3]   fp32   (20,736)
// w:        [128][128][3][3]  fp32   (147,456)
// out:      [8][128][64][64]  fp32
//
// Workspace budget: assume ws_size may be as small as out bytes (16 MiB).
// Layout: off fp32 (2,359,296 B) @ 0 ; xT bf16 (8,388,608 B) @ 2,359,296.
// Total 10,747,904 B < 16 MiB.

// ------------------------------------------------------------------
// Kernel A: transpose x NCHW -> NHWC bf16 (xT[b][h][w][c]) for
// coalesced bilinear gathers (lane = channel).
// ------------------------------------------------------------------
__global__ __launch_bounds__(256) void transpose_nchw_nhwc(
    const float* __restrict__ x, __hip_bfloat16* __restrict__ xT) {
    __shared__ float tile[128][65];   // +1 pad: conflict-free transpose
    int bh = blockIdx.x;              // b*64 + h
    int b = bh >> 6, h = bh & 63;
    const float* src = x + b * 524288 + h * 64;     // + c*4096 + w
    for (int idx = threadIdx.x; idx < 8192; idx += 256) {
        int c = idx >> 6, w = idx & 63;
        tile[c][w] = src[c * 4096 + w];             // coalesced read
    }
    __syncthreads();
    __hip_bfloat16* dst = xT + (size_t)bh * 8192;   // [w][c]
    for (int idx = threadIdx.x; idx < 8192; idx += 256) {
        int w = idx >> 7, c = idx & 127;
        dst[idx] = __float2bfloat16(tile[c][w]);    // coalesced write
    }
}

// ------------------------------------------------------------------
// Kernel B: offset = conv2d(x, w_offset), stride 1, pad 1, zero-pad.
// offset layout: [b][ch=18][ho][wo], ch = 2*kk (dy) / 2*kk+1 (dx)
// ------------------------------------------------------------------
__global__ __launch_bounds__(256) void offset_conv(
    const float* __restrict__ x, const float* __restrict__ woff,
    float* __restrict__ off) {
    int idx = blockIdx.x * 256 + threadIdx.x;  // ((b*18+oc)*64+ho)*64+wo
    if (idx >= 8 * 18 * 4096) return;
    int wcol = idx & 63;
    int ho = (idx >> 6) & 63;
    int rem = idx >> 12;          // b*18 + oc
    int oc = rem % 18;
    int b = rem / 18;
    const float* xb = x + b * 524288;
    const float* wr = woff + oc * 1152;
    float acc = 0.f;
    for (int c = 0; c < 128; ++c) {
        const float* xc = xb + c * 4096;
        const float* wc = wr + c * 9;
#pragma unroll
        for (int ky = 0; ky < 3; ++ky) {
            int y = ho - 1 + ky;
            if ((unsigned)y >= 64u) continue;
#pragma unroll
            for (int kx = 0; kx < 3; ++kx) {
                int xx = wcol - 1 + kx;
                if ((unsigned)xx >= 64u) continue;
                acc += xc[y * 64 + xx] * wc[ky * 3 + kx];
            }
        }
    }
    off[idx] = acc;
}

// ------------------------------------------------------------------
// Kernel C: deformable conv main.
// Block = 128 threads, 8 consecutive wo positions (same b,ho).
// Phase 1 (t<72): per (p,kk) compute y0,x0,ly,lx from offsets.
// Phase 2: thread t = channel c, bilinear-sample 8*9 bf16 values
//          from xT (coalesced: lane = c contiguous), store fp32 LDS.
// Phase 3: thread t = cout, dot(W[t,1152], S[p,1152]) for 8 positions.
// ------------------------------------------------------------------
__global__ __launch_bounds__(128) void deform_main(
    const __hip_bfloat16* __restrict__ xT, const float* __restrict__ off,
    const float* __restrict__ w, float* __restrict__ out) {
    __shared__ float s_samp[8 * 1152];   // [p][c*9+kk]
    __shared__ int   s_y0[72], s_x0[72];
    __shared__ float s_ly[72], s_lx[72];

    int sp0 = blockIdx.x * 8;            // b*4096 + ho*64 + wo0
    int wo0 = sp0 & 63;
    int ho  = (sp0 >> 6) & 63;
    int b   = sp0 >> 12;
    int t = threadIdx.x;

    if (t < 72) {
        int p = t / 9, kk = t % 9;
        int pos = ho * 64 + wo0 + p;
        float dy = off[(b * 18 + 2 * kk) * 4096 + pos];
        float dx = off[(b * 18 + 2 * kk + 1) * 4096 + pos];
        float py = (float)(ho - 1 + kk / 3) + dy;
        float px = (float)(wo0 + p - 1 + kk % 3) + dx;
        float y0f = floorf(py), x0f = floorf(px);
        s_y0[t] = (int)y0f;
        s_x0[t] = (int)x0f;
        s_ly[t] = py - y0f;
        s_lx[t] = px - x0f;
    }
    __syncthreads();

    // Phase 2: sampling (thread = channel)
    const __hip_bfloat16* xb = xT + b * 524288;   // [h][w][c]
#pragma unroll 1
    for (int p = 0; p < 8; ++p) {
#pragma unroll 1
        for (int kk = 0; kk < 9; ++kk) {
            int i = p * 9 + kk;
            int y0 = s_y0[i], x0 = s_x0[i];
            float ly = s_ly[i], lx = s_lx[i];
            int y1 = y0 + 1, x1 = x0 + 1;
            int y0c = min(max(y0, 0), 63), y1c = min(max(y1, 0), 63);
            int x0c = min(max(x0, 0), 63), x1c = min(max(x1, 0), 63);
            float my0 = (y0 >= 0 && y0 < 64) ? 1.f : 0.f;
            float my1 = (y1 >= 0 && y1 < 64) ? 1.f : 0.f;
            float mx0 = (x0 >= 0 && x0 < 64) ? 1.f : 0.f;
            float mx1 = (x1 >= 0 && x1 < 64) ? 1.f : 0.f;
            float v00 = __bfloat162float(xb[(y0c * 64 + x0c) * 128 + t]) * (my0 * mx0);
            float v01 = __bfloat162float(xb[(y0c * 64 + x1c) * 128 + t]) * (my0 * mx1);
            float v10 = __bfloat162float(xb[(y1c * 64 + x0c) * 128 + t]) * (my1 * mx0);
            float v11 = __bfloat162float(xb[(y1c * 64 + x1c) * 128 + t]) * (my1 * mx1);
            s_samp[p * 1152 + t * 9 + kk] =
                v00 * (1.f - ly) * (1.f - lx) + v01 * (1.f - ly) * lx +
                v10 * ly * (1.f - lx) + v11 * ly * lx;
        }
    }
    __syncthreads();

    // Phase 3: thread = cout; 8-position register block over shared K.
    float acc[8] = {0.f, 0.f, 0.f, 0.f, 0.f, 0.f, 0.f, 0.f};
    const float4* w4 = reinterpret_cast<const float4*>(w) + t * 288;
    const float4* s4 = reinterpret_cast<const float4*>(s_samp);
#pragma unroll 2
    for (int i = 0; i < 288; ++i) {
        float4 wv = w4[i];
#pragma unroll
        for (int p = 0; p < 8; ++p) {
            float4 sv = s4[p * 288 + i];
            acc[p] += wv.x * sv.x + wv.y * sv.y + wv.z * sv.z + wv.w * sv.w;
        }
    }
    float* ob = out + (b * 128 + t) * 4096 + ho * 64 + wo0;
    *reinterpret_cast<float4*>(ob)     = make_float4(acc[0], acc[1], acc[2], acc[3]);
    *reinterpret_cast<float4*>(ob + 4) = make_float4(acc[4], acc[5], acc[6], acc[7]);
}

// ------------------------------------------------------------------
extern "C" void kernel_launch(void* const* d_in, const int* in_sizes, int n_in,
                              void* d_out, int out_size, void* d_ws, size_t ws_size,
                              hipStream_t stream) {
    const float* x     = (const float*)d_in[0];
    const float* woff  = (const float*)d_in[1];
    const float* w     = (const float*)d_in[2];
    float* out = (float*)d_out;

    float* off = (float*)d_ws;                                   // 2,359,296 B
    __hip_bfloat16* xT = (__hip_bfloat16*)((char*)d_ws + 2359296); // 8,388,608 B

    transpose_nchw_nhwc<<<512, 256, 0, stream>>>(x, xT);
    offset_conv<<<2304, 256, 0, stream>>>(x, woff, off);
    deform_main<<<4096, 128, 0, stream>>>(xT, off, w, out);
}

// Round 4
// 335.903 us; speedup vs baseline: 2.1532x; 2.1532x over previous
//
#include <hip/hip_runtime.h>
#include <hip/hip_bf16.h>
#include <math.h>

// B=8, Cin=Cout=128, H=W=64, K=3, S=1, P=1
// ws layout (total 10,747,904 B == R2-proven-safe size):
//   offT fp32 [8][4096 pos][18]  @ 0          (2,359,296 B)
//   xT   bf16 [8][64][64][128]   @ 2,359,296  (8,388,608 B)

typedef short bf16x8 __attribute__((ext_vector_type(8)));
typedef float f32x4  __attribute__((ext_vector_type(4)));

__device__ __forceinline__ unsigned short f2bf(float f) {
    unsigned u = __float_as_uint(f);
    u += 0x7fffu + ((u >> 16) & 1u);           // RNE (inputs are finite/sane)
    return (unsigned short)(u >> 16);
}
__device__ __forceinline__ float bflo(unsigned u) { return __uint_as_float(u << 16); }
__device__ __forceinline__ float bfhi(unsigned u) { return __uint_as_float(u & 0xffff0000u); }

// ------------------------------------------------------------------
// Kernel A: NCHW fp32 -> NHWC bf16 (pair-packed uint writes).
// ------------------------------------------------------------------
__global__ __launch_bounds__(256) void transpose_nchw_nhwc(
    const float* __restrict__ x, unsigned* __restrict__ xT) {
    __shared__ float tile[128][65];
    int bh = blockIdx.x;                 // b*64 + h
    int b = bh >> 6, h = bh & 63;
    const float* src = x + b * 524288 + h * 64;
    for (int idx = threadIdx.x; idx < 8192; idx += 256) {
        int c = idx >> 6, ww = idx & 63;
        tile[c][ww] = src[c * 4096 + ww];
    }
    __syncthreads();
    unsigned* dst = xT + (size_t)bh * 4096;   // [w][c/2] as uint
    for (int idx = threadIdx.x; idx < 4096; idx += 256) {
        int ww = idx >> 6, c2 = (idx & 63) * 2;
        unsigned lo = f2bf(tile[c2][ww]);
        unsigned hi = f2bf(tile[c2 + 1][ww]);
        dst[idx] = lo | (hi << 16);
    }
}

// ------------------------------------------------------------------
// Kernel B: offset conv as implicit-GEMM MFMA.
// Block = (b,ho) row: M = 64 pos (4 waves x 16), N = 18 pad 32, K = 1152.
// A = NHWC xT window reads (dwordx4, per-lane edge mask), B = w_offset gather.
// Output offT[b][pos][18] fp32.
// ------------------------------------------------------------------
__global__ __launch_bounds__(256) void offset_mfma(
    const __hip_bfloat16* __restrict__ xT, const float* __restrict__ woff,
    float* __restrict__ offT) {
    int blk = blockIdx.x;                // b*64 + ho
    int b = blk >> 6, ho = blk & 63;
    int t = threadIdx.x, l = t & 63, w = t >> 6;
    int lr = l & 15, lg = l >> 4;
    const char* xb = (const char*)xT + (size_t)b * 1048576;
    f32x4 acc[2] = {{0.f,0.f,0.f,0.f},{0.f,0.f,0.f,0.f}};

    for (int kk = 0; kk < 9; ++kk) {
        int y = ho + kk / 3 - 1;
        if ((unsigned)y >= 64u) continue;            // whole-row zero: skip
        int xcol = w * 16 + lr + kk % 3 - 1;
        bool vx = (unsigned)xcol < 64u;
        for (int kg = 0; kg < 4; ++kg) {
            int c0 = kg * 32 + lg * 8;
            bf16x8 A = {};
            if (vx) A = *(const bf16x8*)(xb + ((y * 64 + xcol) * 128 + c0) * 2);
#pragma unroll
            for (int n = 0; n < 2; ++n) {
                int oc = n * 16 + lr;
                bf16x8 Bf = {};
                if (oc < 18) {
                    const float* wp = woff + oc * 1152 + kk;
#pragma unroll
                    for (int j = 0; j < 8; ++j)
                        Bf[j] = (short)f2bf(wp[(c0 + j) * 9]);
                }
                acc[n] = __builtin_amdgcn_mfma_f32_16x16x32_bf16(A, Bf, acc[n], 0, 0, 0);
            }
        }
    }
    // D: row = pos = w*16 + lg*4 + r, col = oc = n*16 + lr
    float* orow = offT + (size_t)b * 4096 * 18;
    int posb = ho * 64 + w * 16 + lg * 4;
#pragma unroll
    for (int n = 0; n < 2; ++n) {
        int oc = n * 16 + lr;
        if (oc < 18) {
#pragma unroll
            for (int r = 0; r < 4; ++r)
                orow[(posb + r) * 18 + oc] = acc[n][r];
        }
    }
}

// ------------------------------------------------------------------
// Kernel C: deformable conv main, implicit-GEMM MFMA.
// Block = (b,ho) row, 512 thr (8 waves). Wave w: cout tile [w*16, w*16+16),
// all 64 pos (4 n-frags). Per kk: sample 64x128 bf16 tile into swizzled LDS,
// then 16 MFMA/wave. Meta (corner offsets + mask-folded weights) precomputed.
// ------------------------------------------------------------------
__global__ __launch_bounds__(512) void deform_mfma(
    const __hip_bfloat16* __restrict__ xT, const float* __restrict__ offT,
    const float* __restrict__ wq, float* __restrict__ out) {
    __shared__ unsigned short s_tile[8192];   // [64 pos][128 c], 16B-slot XOR swizzle
    __shared__ int4   s_pix[576];             // [kk][pos] corner byte offsets
    __shared__ float4 s_wt[576];              // [kk][pos] mask-folded weights

    int blk = blockIdx.x;                // b*64 + ho
    int b = blk >> 6, ho = blk & 63;
    int t = threadIdx.x, l = t & 63, w = t >> 6;
    int lr = l & 15, lg = l >> 4;
    const char* xb = (const char*)xT + (size_t)b * 1048576;

    // Phase 0: bilinear meta for all (kk, pos)
    for (int e = t; e < 576; e += 512) {
        int pos = e & 63, kk = e >> 6;
        const float* op = offT + ((size_t)(b * 4096 + ho * 64 + pos)) * 18 + kk * 2;
        float dy = op[0], dx = op[1];
        float py = (float)(ho + kk / 3 - 1) + dy;
        float px = (float)(pos + kk % 3 - 1) + dx;
        float y0f = floorf(py), x0f = floorf(px);
        float ly = py - y0f, lx = px - x0f;
        int y0 = (int)y0f, x0 = (int)x0f;
        int y1 = y0 + 1, x1 = x0 + 1;
        float my0 = ((unsigned)y0 < 64u) ? 1.f : 0.f;
        float my1 = ((unsigned)y1 < 64u) ? 1.f : 0.f;
        float mx0 = ((unsigned)x0 < 64u) ? 1.f : 0.f;
        float mx1 = ((unsigned)x1 < 64u) ? 1.f : 0.f;
        int y0c = min(max(y0, 0), 63), y1c = min(max(y1, 0), 63);
        int x0c = min(max(x0, 0), 63), x1c = min(max(x1, 0), 63);
        s_pix[e] = make_int4((y0c * 64 + x0c) * 256, (y0c * 64 + x1c) * 256,
                             (y1c * 64 + x0c) * 256, (y1c * 64 + x1c) * 256);
        s_wt[e] = make_float4((1.f - ly) * (1.f - lx) * my0 * mx0,
                              (1.f - ly) * lx * my0 * mx1,
                              ly * (1.f - lx) * my1 * mx0,
                              ly * lx * my1 * mx1);
    }
    __syncthreads();

    f32x4 acc[4] = {{0.f,0.f,0.f,0.f},{0.f,0.f,0.f,0.f},{0.f,0.f,0.f,0.f},{0.f,0.f,0.f,0.f}};
    char* tp = (char*)s_tile;
    int pg = t >> 5;          // pos group 0..15 (half-wave shares pos)
    int cq = t & 31;          // c-quad: c = cq*4
    int cb = w * 16;          // wave's cout base

    for (int kk = 0; kk < 9; ++kk) {
        // ---- sampling: 4 (pos) x 4 c values per thread ----
#pragma unroll
        for (int i = 0; i < 4; ++i) {
            int pos = pg + i * 16;
            int e = kk * 64 + pos;
            int4 pix = s_pix[e];
            float4 wt = s_wt[e];
            uint2 u00 = *(const uint2*)(xb + pix.x + cq * 8);
            uint2 u01 = *(const uint2*)(xb + pix.y + cq * 8);
            uint2 u10 = *(const uint2*)(xb + pix.z + cq * 8);
            uint2 u11 = *(const uint2*)(xb + pix.w + cq * 8);
            float r0 = wt.x * bflo(u00.x) + wt.y * bflo(u01.x) + wt.z * bflo(u10.x) + wt.w * bflo(u11.x);
            float r1 = wt.x * bfhi(u00.x) + wt.y * bfhi(u01.x) + wt.z * bfhi(u10.x) + wt.w * bfhi(u11.x);
            float r2 = wt.x * bflo(u00.y) + wt.y * bflo(u01.y) + wt.z * bflo(u10.y) + wt.w * bflo(u11.y);
            float r3 = wt.x * bfhi(u00.y) + wt.y * bfhi(u01.y) + wt.z * bfhi(u10.y) + wt.w * bfhi(u11.y);
            uint2 o;
            o.x = (unsigned)f2bf(r0) | ((unsigned)f2bf(r1) << 16);
            o.y = (unsigned)f2bf(r2) | ((unsigned)f2bf(r3) << 16);
            // swizzled write: slot = cq>>1 (16B), sub = (cq&1)*8
            *(uint2*)(tp + pos * 256 + (((cq >> 1) ^ (pos & 7)) << 4) + (cq & 1) * 8) = o;
        }
        // ---- A-frag gather (independent of s_tile; overlaps pre-barrier) ----
        bf16x8 Af[4];
        {
            const float* wp = wq + (cb + lr) * 1152 + kk;
#pragma unroll
            for (int kg = 0; kg < 4; ++kg) {
                int c0 = kg * 32 + lg * 8;
#pragma unroll
                for (int j = 0; j < 8; ++j)
                    Af[kg][j] = (short)f2bf(wp[(c0 + j) * 9]);
            }
        }
        __syncthreads();
        // ---- MFMA: 4 kg x 4 n ----
#pragma unroll
        for (int kg = 0; kg < 4; ++kg) {
            int slot = kg * 4 + lg;
#pragma unroll
            for (int n = 0; n < 4; ++n) {
                int row = n * 16 + lr;
                bf16x8 Bf = *(const bf16x8*)(tp + row * 256 + ((slot ^ (row & 7)) << 4));
                acc[n] = __builtin_amdgcn_mfma_f32_16x16x32_bf16(Af[kg], Bf, acc[n], 0, 0, 0);
            }
        }
        __syncthreads();
    }

    // Epilogue: D row = cout = cb + lg*4 + r, col = pos = n*16 + lr
    float* ob = out + ((size_t)(b * 128 + cb + lg * 4)) * 4096 + ho * 64;
#pragma unroll
    for (int n = 0; n < 4; ++n) {
#pragma unroll
        for (int r = 0; r < 4; ++r)
            ob[r * 4096 + n * 16 + lr] = acc[n][r];
    }
}

// ------------------------------------------------------------------
extern "C" void kernel_launch(void* const* d_in, const int* in_sizes, int n_in,
                              void* d_out, int out_size, void* d_ws, size_t ws_size,
                              hipStream_t stream) {
    const float* x    = (const float*)d_in[0];
    const float* woff = (const float*)d_in[1];
    const float* w    = (const float*)d_in[2];
    float* out = (float*)d_out;

    float* offT = (float*)d_ws;                                      // 2,359,296 B
    __hip_bfloat16* xT = (__hip_bfloat16*)((char*)d_ws + 2359296);   // 8,388,608 B

    transpose_nchw_nhwc<<<512, 256, 0, stream>>>(x, (unsigned*)xT);
    offset_mfma<<<512, 256, 0, stream>>>(xT, woff, offT);
    deform_mfma<<<512, 512, 0, stream>>>(xT, offT, w, out);
}

// Round 5
// 140.165 us; speedup vs baseline: 5.1601x; 2.3965x over previous
//
#include <hip/hip_runtime.h>
#include <hip/hip_bf16.h>
#include <math.h>

// B=8, Cin=Cout=128, H=W=64, K=3, S=1, P=1
// ws layout (total 9,936,896 B < R2-proven-safe 10,747,904 B):
//   wT    bf16 [9][128 co][128 c]   @ 0          (294,912 B)
//   woffT bf16 [9][32 oc][128 c]    @ 294,912    ( 73,728 B)  oc>=18 zero
//   offT  f16  [8][4096 pos][18]    @ 368,640    (1,179,648 B)
//   xT    bf16 [8][64][64][128]     @ 1,548,288  (8,388,608 B)

typedef short bf16x8 __attribute__((ext_vector_type(8)));
typedef float f32x4  __attribute__((ext_vector_type(4)));

__device__ __forceinline__ unsigned short f2bf(float f) {
    unsigned u = __float_as_uint(f);
    u += 0x7fffu + ((u >> 16) & 1u);           // RNE
    return (unsigned short)(u >> 16);
}
__device__ __forceinline__ float bflo(unsigned u) { return __uint_as_float(u << 16); }
__device__ __forceinline__ float bfhi(unsigned u) { return __uint_as_float(u & 0xffff0000u); }

// ------------------------------------------------------------------
// Kernel P: repack w and w_offset into MFMA-fragment-ready bf16.
//   wT[(kk*128+co)*128+c]   = bf16(w[co*1152 + c*9 + kk])
//   woffT[(kk*32+oc)*128+c] = bf16(woff[oc*1152 + c*9 + kk]), 0 if oc>=18
// Tiny tensors (590 KB + 83 KB reads) — uncoalesced reads acceptable.
// ------------------------------------------------------------------
__global__ __launch_bounds__(256) void prep_weights(
    const float* __restrict__ w, const float* __restrict__ woff,
    unsigned short* __restrict__ wT, unsigned short* __restrict__ woffT) {
    int idx = blockIdx.x * 256 + threadIdx.x;
    if (idx < 147456) {
        int c  = idx & 127;
        int co = (idx >> 7) & 127;
        int kk = idx >> 14;
        wT[idx] = f2bf(w[co * 1152 + c * 9 + kk]);
    }
    if (idx < 36864) {
        int c  = idx & 127;
        int oc = (idx >> 7) & 31;
        int kk = idx >> 12;
        woffT[idx] = (oc < 18) ? f2bf(woff[oc * 1152 + c * 9 + kk]) : (unsigned short)0;
    }
}

// ------------------------------------------------------------------
// Kernel A: NCHW fp32 -> NHWC bf16 (pair-packed uint writes).
// ------------------------------------------------------------------
__global__ __launch_bounds__(256) void transpose_nchw_nhwc(
    const float* __restrict__ x, unsigned* __restrict__ xT) {
    __shared__ float tile[128][65];
    int bh = blockIdx.x;                 // b*64 + h
    int b = bh >> 6, h = bh & 63;
    const float* src = x + b * 524288 + h * 64;
    for (int idx = threadIdx.x; idx < 8192; idx += 256) {
        int c = idx >> 6, ww = idx & 63;
        tile[c][ww] = src[c * 4096 + ww];
    }
    __syncthreads();
    unsigned* dst = xT + (size_t)bh * 4096;   // [w][c/2] as uint
    for (int idx = threadIdx.x; idx < 4096; idx += 256) {
        int ww = idx >> 6, c2 = (idx & 63) * 2;
        unsigned lo = f2bf(tile[c2][ww]);
        unsigned hi = f2bf(tile[c2 + 1][ww]);
        dst[idx] = lo | (hi << 16);
    }
}

// ------------------------------------------------------------------
// Kernel B: offset conv as implicit-GEMM MFMA.
// Block = (b,ho) row: M = 64 pos (4 waves x 16), N = 18 pad 32, K = 1152.
// A = NHWC xT window reads; B = woffT coalesced b128 loads (pre-padded).
// Output offT[b][pos][18] f16.
// ------------------------------------------------------------------
__global__ __launch_bounds__(256) void offset_mfma(
    const __hip_bfloat16* __restrict__ xT, const unsigned short* __restrict__ woffT,
    _Float16* __restrict__ offT) {
    int blk = blockIdx.x;                // b*64 + ho
    int b = blk >> 6, ho = blk & 63;
    int t = threadIdx.x, l = t & 63, w = t >> 6;
    int lr = l & 15, lg = l >> 4;
    const char* xb = (const char*)xT + (size_t)b * 1048576;
    f32x4 acc[2] = {{0.f,0.f,0.f,0.f},{0.f,0.f,0.f,0.f}};

    for (int kk = 0; kk < 9; ++kk) {
        int y = ho + kk / 3 - 1;
        if ((unsigned)y >= 64u) continue;            // A row all-zero: skip
        int xcol = w * 16 + lr + kk % 3 - 1;
        bool vx = (unsigned)xcol < 64u;
#pragma unroll
        for (int kg = 0; kg < 4; ++kg) {
            int c0 = kg * 32 + lg * 8;
            bf16x8 A = {};
            if (vx) A = *(const bf16x8*)(xb + ((y * 64 + xcol) * 128 + c0) * 2);
#pragma unroll
            for (int n = 0; n < 2; ++n) {
                bf16x8 Bf = *(const bf16x8*)(woffT + (kk * 32 + n * 16 + lr) * 128 + c0);
                acc[n] = __builtin_amdgcn_mfma_f32_16x16x32_bf16(A, Bf, acc[n], 0, 0, 0);
            }
        }
    }
    // D: row = pos = w*16 + lg*4 + r, col = oc = n*16 + lr
    _Float16* orow = offT + (size_t)b * 4096 * 18;
    int posb = ho * 64 + w * 16 + lg * 4;
#pragma unroll
    for (int n = 0; n < 2; ++n) {
        int oc = n * 16 + lr;
        if (oc < 18) {
#pragma unroll
            for (int r = 0; r < 4; ++r)
                orow[(posb + r) * 18 + oc] = (_Float16)acc[n][r];
        }
    }
}

// ------------------------------------------------------------------
// Kernel C: deformable conv main, implicit-GEMM MFMA.
// Block = (b,ho) row, 512 thr (8 waves). Wave w: cout tile [w*16, w*16+16),
// all 64 pos. Per kk: sample 64x128 bf16 tile into swizzled LDS, A-frags
// from wT via 4 coalesced b128 loads, then 16 MFMA/wave.
// ------------------------------------------------------------------
__global__ __launch_bounds__(512) void deform_mfma(
    const __hip_bfloat16* __restrict__ xT, const _Float16* __restrict__ offT,
    const unsigned short* __restrict__ wT, float* __restrict__ out) {
    __shared__ unsigned short s_tile[8192];   // [64 pos][128 c], 16B-slot XOR swizzle
    __shared__ int4   s_pix[576];             // [kk][pos] corner byte offsets
    __shared__ float4 s_wt[576];              // [kk][pos] mask-folded weights

    int blk = blockIdx.x;                // b*64 + ho
    int b = blk >> 6, ho = blk & 63;
    int t = threadIdx.x, l = t & 63, w = t >> 6;
    int lr = l & 15, lg = l >> 4;
    const char* xb = (const char*)xT + (size_t)b * 1048576;

    // Phase 0: bilinear meta for all (kk, pos). offT read as uint pairs:
    // element pair (2kk, 2kk+1) of 18 = uint index pos*9 + kk (4B aligned).
    const unsigned* ou = (const unsigned*)offT;
    for (int e = t; e < 576; e += 512) {
        int pos = e & 63, kk = e >> 6;
        unsigned pr = ou[(size_t)(b * 4096 + ho * 64 + pos) * 9 + kk];
        union { unsigned u; _Float16 h[2]; } cv; cv.u = pr;
        float dy = (float)cv.h[0], dx = (float)cv.h[1];
        float py = (float)(ho + kk / 3 - 1) + dy;
        float px = (float)(pos + kk % 3 - 1) + dx;
        float y0f = floorf(py), x0f = floorf(px);
        float ly = py - y0f, lx = px - x0f;
        int y0 = (int)y0f, x0 = (int)x0f;
        int y1 = y0 + 1, x1 = x0 + 1;
        float my0 = ((unsigned)y0 < 64u) ? 1.f : 0.f;
        float my1 = ((unsigned)y1 < 64u) ? 1.f : 0.f;
        float mx0 = ((unsigned)x0 < 64u) ? 1.f : 0.f;
        float mx1 = ((unsigned)x1 < 64u) ? 1.f : 0.f;
        int y0c = min(max(y0, 0), 63), y1c = min(max(y1, 0), 63);
        int x0c = min(max(x0, 0), 63), x1c = min(max(x1, 0), 63);
        s_pix[e] = make_int4((y0c * 64 + x0c) * 256, (y0c * 64 + x1c) * 256,
                             (y1c * 64 + x0c) * 256, (y1c * 64 + x1c) * 256);
        s_wt[e] = make_float4((1.f - ly) * (1.f - lx) * my0 * mx0,
                              (1.f - ly) * lx * my0 * mx1,
                              ly * (1.f - lx) * my1 * mx0,
                              ly * lx * my1 * mx1);
    }
    __syncthreads();

    f32x4 acc[4] = {{0.f,0.f,0.f,0.f},{0.f,0.f,0.f,0.f},{0.f,0.f,0.f,0.f},{0.f,0.f,0.f,0.f}};
    char* tp = (char*)s_tile;
    int pg = t >> 5;          // pos group 0..15 (half-wave shares pos)
    int cq = t & 31;          // c-quad: c = cq*4
    int cb = w * 16;          // wave's cout base

    for (int kk = 0; kk < 9; ++kk) {
        // ---- sampling: 4 (pos) x 4 c values per thread ----
#pragma unroll
        for (int i = 0; i < 4; ++i) {
            int pos = pg + i * 16;
            int e = kk * 64 + pos;
            int4 pix = s_pix[e];
            float4 wt = s_wt[e];
            uint2 u00 = *(const uint2*)(xb + pix.x + cq * 8);
            uint2 u01 = *(const uint2*)(xb + pix.y + cq * 8);
            uint2 u10 = *(const uint2*)(xb + pix.z + cq * 8);
            uint2 u11 = *(const uint2*)(xb + pix.w + cq * 8);
            float r0 = wt.x * bflo(u00.x) + wt.y * bflo(u01.x) + wt.z * bflo(u10.x) + wt.w * bflo(u11.x);
            float r1 = wt.x * bfhi(u00.x) + wt.y * bfhi(u01.x) + wt.z * bfhi(u10.x) + wt.w * bfhi(u11.x);
            float r2 = wt.x * bflo(u00.y) + wt.y * bflo(u01.y) + wt.z * bflo(u10.y) + wt.w * bflo(u11.y);
            float r3 = wt.x * bfhi(u00.y) + wt.y * bfhi(u01.y) + wt.z * bfhi(u10.y) + wt.w * bfhi(u11.y);
            uint2 o;
            o.x = (unsigned)f2bf(r0) | ((unsigned)f2bf(r1) << 16);
            o.y = (unsigned)f2bf(r2) | ((unsigned)f2bf(r3) << 16);
            *(uint2*)(tp + pos * 256 + (((cq >> 1) ^ (pos & 7)) << 4) + (cq & 1) * 8) = o;
        }
        // ---- A-frags: 4 coalesced b128 loads from wT (L2-resident) ----
        bf16x8 Af[4];
        {
            const unsigned short* wr = wT + ((kk * 128 + cb + lr) << 7) + lg * 8;
#pragma unroll
            for (int kg = 0; kg < 4; ++kg)
                Af[kg] = *(const bf16x8*)(wr + kg * 32);
        }
        __syncthreads();
        // ---- MFMA: 4 kg x 4 n ----
#pragma unroll
        for (int kg = 0; kg < 4; ++kg) {
            int slot = kg * 4 + lg;
#pragma unroll
            for (int n = 0; n < 4; ++n) {
                int row = n * 16 + lr;
                bf16x8 Bf = *(const bf16x8*)(tp + row * 256 + ((slot ^ (row & 7)) << 4));
                acc[n] = __builtin_amdgcn_mfma_f32_16x16x32_bf16(Af[kg], Bf, acc[n], 0, 0, 0);
            }
        }
        __syncthreads();
    }

    // Epilogue: D row = cout = cb + lg*4 + r, col = pos = n*16 + lr
    float* ob = out + ((size_t)(b * 128 + cb + lg * 4)) * 4096 + ho * 64;
#pragma unroll
    for (int n = 0; n < 4; ++n) {
#pragma unroll
        for (int r = 0; r < 4; ++r)
            ob[r * 4096 + n * 16 + lr] = acc[n][r];
    }
}

// ------------------------------------------------------------------
extern "C" void kernel_launch(void* const* d_in, const int* in_sizes, int n_in,
                              void* d_out, int out_size, void* d_ws, size_t ws_size,
                              hipStream_t stream) {
    const float* x    = (const float*)d_in[0];
    const float* woff = (const float*)d_in[1];
    const float* w    = (const float*)d_in[2];
    float* out = (float*)d_out;

    unsigned short* wT    = (unsigned short*)d_ws;                    // 294,912 B
    unsigned short* woffT = (unsigned short*)((char*)d_ws + 294912);  //  73,728 B
    _Float16*       offT  = (_Float16*)((char*)d_ws + 368640);        // 1,179,648 B
    __hip_bfloat16* xT    = (__hip_bfloat16*)((char*)d_ws + 1548288); // 8,388,608 B

    prep_weights<<<576, 256, 0, stream>>>(w, woff, wT, woffT);
    transpose_nchw_nhwc<<<512, 256, 0, stream>>>(x, (unsigned*)xT);
    offset_mfma<<<512, 256, 0, stream>>>(xT, woffT, offT);
    deform_mfma<<<512, 512, 0, stream>>>(xT, offT, wT, out);
}